// Round 1
// baseline (256.301 us; speedup 1.0000x reference)
//
#include <hip/hip_runtime.h>
#include <stdint.h>

typedef unsigned short u16;
typedef __attribute__((ext_vector_type(4))) float  f32x4;
typedef __attribute__((ext_vector_type(8))) short  short8;
typedef __attribute__((ext_vector_type(8))) u16    u16x8;
typedef __attribute__((ext_vector_type(4))) u16    u16x4;
typedef __attribute__((ext_vector_type(4))) float  fv4;

#define T_LEN 1024
#define EMB   1024
#define SPAD  1088   // padded src len (17*64), valid 0..1024
#define M_ROWS 4096  // T*B

// workspace offsets (bytes)
#define OFF_QX   (0ull)          // bf16 query    [4096][1024]          8 MB
#define OFF_WT   (8388608ull)    // bf16 W^T x4   [4][1024][1024]       8 MB
#define OFF_QB   (16777216ull)   // bf16 q_r      [64][1024][64]        8 MB
#define OFF_KB   (25165824ull)   // bf16 k_r      [64][1088][64]        8.5 MB
#define OFF_VT   (34078720ull)   // bf16 v_r^T    [64][64][1088]        8.5 MB
#define OFF_AT   (42991616ull)   // bf16 attn     [4096][1024]          8 MB
#define OFF_GATE (51380224ull)   // f32 gate      [64][1024]
#define OFF_PB   (51642368ull)   // f32 pb table  [16][2048]

__device__ __forceinline__ u16 f2bf(float f) {
  uint32_t u = __builtin_bit_cast(uint32_t, f);
  u += 0x7FFFu + ((u >> 16) & 1u);
  return (u16)(u >> 16);
}
__device__ __forceinline__ float bf2f(u16 s) {
  uint32_t u = ((uint32_t)s) << 16;
  return __builtin_bit_cast(float, u);
}
__device__ __forceinline__ void gld_lds16(const void* gp, void* lp) {
  __builtin_amdgcn_global_load_lds(
      (const __attribute__((address_space(1))) uint32_t*)(uintptr_t)(gp),
      (__attribute__((address_space(3))) uint32_t*)(uintptr_t)(lp),
      16, 0, 0);
}

// ---------------- query f32 -> bf16 (straight copy-convert) ----------------
__global__ void k_convert_q(const float* __restrict__ q, u16* __restrict__ qx) {
  int i = blockIdx.x * 256 + threadIdx.x;          // 1,048,576 chunks of 4
  fv4 v = *((const fv4*)q + i);
  u16x4 o = { f2bf(v[0]), f2bf(v[1]), f2bf(v[2]), f2bf(v[3]) };
  *((u16x4*)qx + i) = o;
}

// ---------------- weight transpose + convert: wt[z][n][k] = w_z[k][n] -------
__global__ void k_transw(const float* __restrict__ w0, const float* __restrict__ w1,
                         const float* __restrict__ w2, const float* __restrict__ w3,
                         u16* __restrict__ wt) {
  __shared__ float tile[32][33];
  const int z = blockIdx.z;
  const float* w = (z == 0) ? w0 : (z == 1) ? w1 : (z == 2) ? w2 : w3;
  const int r0 = blockIdx.y * 32, c0 = blockIdx.x * 32;
  const int tx = threadIdx.x, ty = threadIdx.y;
  #pragma unroll
  for (int j = 0; j < 32; j += 8)
    tile[ty + j][tx] = w[(size_t)(r0 + ty + j) * EMB + c0 + tx];
  __syncthreads();
  u16* o = wt + (size_t)z * EMB * EMB;
  #pragma unroll
  for (int j = 0; j < 32; j += 8)
    o[(size_t)(c0 + ty + j) * EMB + r0 + tx] = f2bf(tile[tx][ty + j]);
}

// ---------------- T5 bucket -> bias table: pbtab[h][rel+1023] ---------------
__global__ void k_pb(const float* __restrict__ rel_emb, float* __restrict__ pbtab) {
  int i = blockIdx.x * 256 + threadIdx.x;   // 0..2047
  int rel = i - 1023;                       // u_k - u_q
  int bucket = (rel > 0) ? 16 : 0;
  int r = rel < 0 ? -rel : rel;
  int bidx;
  if (r < 8) bidx = r;
  else {
    float lf = __logf((float)r / 8.0f + 1e-6f) * (1.0f / logf(16.0f)) * 8.0f;
    int large = 8 + (int)lf;
    bidx = large < 15 ? large : 15;
  }
  bucket += bidx;
  #pragma unroll
  for (int h = 0; h < 16; ++h) pbtab[h * 2048 + i] = rel_emb[bucket * 16 + h];
}

// ---------------- m97-style 128x128 bf16 GEMM core (B^T input) --------------
__device__ __forceinline__ void gemm_tile(const u16* __restrict__ A, const u16* __restrict__ Bt,
                                          int m0, int n0, u16* As, u16* Bs, f32x4 acc[4][4]) {
  const int tid = threadIdx.x;
  const int lane = tid & 63, wid = tid >> 6;
  const int wm = wid >> 1, wn = wid & 1;
  const int l15 = lane & 15, l4 = lane >> 4;
  for (int kt = 0; kt < EMB; kt += 32) {
    #pragma unroll
    for (int i = 0; i < 2; ++i) {
      int cw = wid * 64 + i * 256;   // wave-uniform chunk base
      int c = cw + lane;
      int row = c >> 2, cb = c & 3;
      gld_lds16(A  + (size_t)(m0 + row) * EMB + kt + cb * 8, (char*)As + (size_t)cw * 16);
      gld_lds16(Bt + (size_t)(n0 + row) * EMB + kt + cb * 8, (char*)Bs + (size_t)cw * 16);
    }
    __syncthreads();
    short8 a[4], b[4];
    #pragma unroll
    for (int f = 0; f < 4; ++f) {
      a[f] = *(const short8*)(As + (wm * 64 + f * 16 + l15) * 32 + l4 * 8);
      b[f] = *(const short8*)(Bs + (wn * 64 + f * 16 + l15) * 32 + l4 * 8);
    }
    #pragma unroll
    for (int mi = 0; mi < 4; ++mi)
      #pragma unroll
      for (int ni = 0; ni < 4; ++ni)
        acc[mi][ni] = __builtin_amdgcn_mfma_f32_16x16x32_bf16(a[mi], b[ni], acc[mi][ni], 0, 0, 0);
    __syncthreads();
  }
}

// ---------------- QKV projection GEMM with scrambled-scatter epilogue -------
__global__ __launch_bounds__(256, 2) void k_qkv_gemm(const u16* __restrict__ qx, const u16* __restrict__ wt,
    const float* __restrict__ qbias, const float* __restrict__ kbias, const float* __restrict__ vbias,
    u16* __restrict__ qb, u16* __restrict__ kb, u16* __restrict__ vt) {
  __shared__ u16 lds[8192];
  const int z = blockIdx.z;
  f32x4 acc[4][4];
  #pragma unroll
  for (int i = 0; i < 4; ++i)
    #pragma unroll
    for (int j = 0; j < 4; ++j) acc[i][j] = (f32x4){0.f, 0.f, 0.f, 0.f};
  const int m0 = blockIdx.y * 128, n0 = blockIdx.x * 128;
  gemm_tile(qx, wt + (size_t)z * EMB * EMB, m0, n0, lds, lds + 4096, acc);
  const float* bias = (z == 0) ? qbias : (z == 1) ? kbias : vbias;
  const int lane = threadIdx.x & 63, wid = threadIdx.x >> 6;
  const int wm = wid >> 1, wn = wid & 1, l15 = lane & 15, l4 = lane >> 4;
  #pragma unroll
  for (int ni = 0; ni < 4; ++ni) {
    int col = n0 + wn * 64 + ni * 16 + l15;
    float bv = bias[col];
    int h = col >> 6, d = col & 63;
    #pragma unroll
    for (int mi = 0; mi < 4; ++mi) {
      #pragma unroll
      for (int r = 0; r < 4; ++r) {
        int row = m0 + wm * 64 + mi * 16 + l4 * 4 + r;
        int t = row >> 2, b = row & 3;     // input rows are (t,b) interleaved
        float v = acc[mi][ni][r] + bv;
        if (z == 0) {
          // fairseq reshape (len=1024): x = b*16 + t>>6, u = (t&63)*16 + h
          int x = b * 16 + (t >> 6), u = ((t & 63) << 4) + h;
          qb[((size_t)x * 1024 + u) * 64 + d] = f2bf(v * (1.0f / 256.0f)); // *scaling/ALPHA
        } else {
          // len=1025 scramble: w = s*16+h; x = b*16 + w/1025; u = w%1025
          int w = t * 16 + h;
          int j = w / 1025;
          int u = w - j * 1025;
          int x = b * 16 + j;
          if (z == 1) kb[((size_t)x * SPAD + u) * 64 + d] = f2bf(v);
          else        vt[((size_t)x * 64 + d) * SPAD + u] = f2bf(v);
        }
      }
    }
  }
}

// ---------------- bias_k / bias_v rows (land only in j=15 slots) ------------
__global__ void k_biaskv(const float* __restrict__ bias_k, const float* __restrict__ bias_v,
                         u16* __restrict__ kb, u16* __restrict__ vt) {
  int i = blockIdx.x * 256 + threadIdx.x;  // 0..4095
  int b = i >> 10, h = (i >> 6) & 15, d = i & 63;
  int x = b * 16 + 15, u = 1009 + h;       // w = 16384+h -> j=15, u=1009+h
  kb[((size_t)x * SPAD + u) * 64 + d] = f2bf(bias_k[h * 64 + d]);
  vt[((size_t)x * 64 + d) * SPAD + u] = f2bf(bias_v[h * 64 + d]);
}

// ---------------- gate[x][u] = sigmoid(q_row . wg + bg) * grep_a[x&15] ------
__global__ void k_gate(const u16* __restrict__ qb, const float* __restrict__ grep_w,
                       const float* __restrict__ grep_b, const float* __restrict__ grep_a,
                       float* __restrict__ gate) {
  int lane = threadIdx.x & 63, wid = threadIdx.x >> 6;
  int item = blockIdx.x * 4 + wid;         // 0..65535 = (x,u)
  int x = item >> 10;
  float wg = 0.f, bg = 0.f;
  #pragma unroll
  for (int j = 0; j < 8; ++j) { wg += grep_w[lane * 8 + j]; bg += grep_b[j]; }
  float qv = bf2f(qb[(size_t)item * 64 + lane]) * 256.0f;  // undo scaling/ALPHA
  float v = qv * wg;
  #pragma unroll
  for (int mk = 32; mk; mk >>= 1) v += __shfl_xor(v, mk);
  if (lane == 0) {
    float s = 1.0f / (1.0f + __expf(-(v + bg)));
    gate[item] = s * grep_a[x & 15];
  }
}

// ---------------- fused flash attention over scrambled (x,u) axes -----------
__global__ __launch_bounds__(256, 2) void k_attn(const u16* __restrict__ qb, const u16* __restrict__ kb,
    const u16* __restrict__ vt, const float* __restrict__ gate, const float* __restrict__ pbt,
    u16* __restrict__ at) {
  __shared__ float pb_s[2048];
  __shared__ u16 Qs[128 * 72];
  __shared__ u16 Ks[64 * 72];
  __shared__ u16 Vs[64 * 72];
  __shared__ u16 Ps[4][32 * 72];
  const int tid = threadIdx.x, lane = tid & 63, wid = tid >> 6;
  const int l15 = lane & 15, l4 = lane >> 4;
  const int x = blockIdx.y, h = x & 15, b = x >> 4;
  const int t0 = blockIdx.x * 128;

  #pragma unroll
  for (int i = 0; i < 2; ++i) {
    int idx = (tid + i * 256) * 4;
    *(fv4*)(pb_s + idx) = *(const fv4*)(pbt + (size_t)h * 2048 + idx);
  }
  #pragma unroll
  for (int i = 0; i < 4; ++i) {
    int c = tid + i * 256, row = c >> 3, cb = c & 7;
    *(u16x8*)(&Qs[row * 72 + cb * 8]) =
        *(const u16x8*)(qb + ((size_t)x * 1024 + t0 + row) * 64 + cb * 8);
  }
  float g[2][4];
  #pragma unroll
  for (int mf = 0; mf < 2; ++mf)
    #pragma unroll
    for (int r = 0; r < 4; ++r)
      g[mf][r] = gate[(size_t)x * 1024 + t0 + wid * 32 + mf * 16 + l4 * 4 + r];

  float m_[2][4], l_[2][4];
  f32x4 O[2][4];
  #pragma unroll
  for (int mf = 0; mf < 2; ++mf)
    #pragma unroll
    for (int r = 0; r < 4; ++r) { m_[mf][r] = -1e30f; l_[mf][r] = 0.f; }
  #pragma unroll
  for (int mf = 0; mf < 2; ++mf)
    #pragma unroll
    for (int df = 0; df < 4; ++df) O[mf][df] = (f32x4){0.f, 0.f, 0.f, 0.f};

  __syncthreads();

  short8 qa[2][2];
  #pragma unroll
  for (int mf = 0; mf < 2; ++mf)
    #pragma unroll
    for (int ks = 0; ks < 2; ++ks)
      qa[mf][ks] = *(const short8*)(&Qs[(wid * 32 + mf * 16 + l15) * 72 + l4 * 8 + ks * 32]);

  for (int ic = 0; ic < 17; ++ic) {
    const int s0 = ic * 64;
    #pragma unroll
    for (int i = 0; i < 2; ++i) {
      int c = tid + i * 256, row = c >> 3, cb = c & 7;
      *(u16x8*)(&Ks[row * 72 + cb * 8]) =
          *(const u16x8*)(kb + ((size_t)x * SPAD + s0 + row) * 64 + cb * 8);
      *(u16x8*)(&Vs[row * 72 + cb * 8]) =
          *(const u16x8*)(vt + ((size_t)x * 64 + row) * SPAD + s0 + cb * 8);
    }
    __syncthreads();
    short8 kf[4][2];
    #pragma unroll
    for (int nf = 0; nf < 4; ++nf)
      #pragma unroll
      for (int ks = 0; ks < 2; ++ks)
        kf[nf][ks] = *(const short8*)(&Ks[(nf * 16 + l15) * 72 + l4 * 8 + ks * 32]);
    f32x4 sc[2][4];
    #pragma unroll
    for (int mf = 0; mf < 2; ++mf)
      #pragma unroll
      for (int nf = 0; nf < 4; ++nf) sc[mf][nf] = (f32x4){0.f, 0.f, 0.f, 0.f};
    #pragma unroll
    for (int mf = 0; mf < 2; ++mf)
      #pragma unroll
      for (int nf = 0; nf < 4; ++nf)
        #pragma unroll
        for (int ks = 0; ks < 2; ++ks)
          sc[mf][nf] = __builtin_amdgcn_mfma_f32_16x16x32_bf16(qa[mf][ks], kf[nf][ks], sc[mf][nf], 0, 0, 0);
    // bias + mask (valid u_k <= 1024)
    #pragma unroll
    for (int mf = 0; mf < 2; ++mf) {
      #pragma unroll
      for (int nf = 0; nf < 4; ++nf) {
        #pragma unroll
        for (int r = 0; r < 4; ++r) {
          int t = t0 + wid * 32 + mf * 16 + l4 * 4 + r;
          int s = s0 + nf * 16 + l15;
          int ridx = s - t + 1023;
          float pbv = pb_s[ridx < 2047 ? ridx : 2047];
          float v = sc[mf][nf][r] + g[mf][r] * pbv;
          sc[mf][nf][r] = (s <= 1024) ? v : -1e30f;
        }
      }
    }
    // online softmax (row reduce across 16 lanes of each group)
    #pragma unroll
    for (int mf = 0; mf < 2; ++mf) {
      #pragma unroll
      for (int r = 0; r < 4; ++r) {
        float rm = fmaxf(fmaxf(sc[mf][0][r], sc[mf][1][r]), fmaxf(sc[mf][2][r], sc[mf][3][r]));
        rm = fmaxf(rm, __shfl_xor(rm, 1));
        rm = fmaxf(rm, __shfl_xor(rm, 2));
        rm = fmaxf(rm, __shfl_xor(rm, 4));
        rm = fmaxf(rm, __shfl_xor(rm, 8));
        float mo = m_[mf][r];
        float mn = fmaxf(mo, rm);
        float cf = __expf(mo - mn);
        m_[mf][r] = mn;
        float rs = 0.f;
        #pragma unroll
        for (int nf = 0; nf < 4; ++nf) {
          float p = __expf(sc[mf][nf][r] - mn);
          sc[mf][nf][r] = p;
          rs += p;
        }
        rs += __shfl_xor(rs, 1);
        rs += __shfl_xor(rs, 2);
        rs += __shfl_xor(rs, 4);
        rs += __shfl_xor(rs, 8);
        l_[mf][r] = l_[mf][r] * cf + rs;
        #pragma unroll
        for (int df = 0; df < 4; ++df) O[mf][df][r] *= cf;
      }
    }
    // P (C/D layout) -> LDS -> A-fragment layout
    u16* Pw = Ps[wid];
    #pragma unroll
    for (int mf = 0; mf < 2; ++mf)
      #pragma unroll
      for (int nf = 0; nf < 4; ++nf)
        #pragma unroll
        for (int r = 0; r < 4; ++r)
          Pw[(mf * 16 + l4 * 4 + r) * 72 + nf * 16 + l15] = f2bf(sc[mf][nf][r]);
    __asm__ volatile("s_waitcnt lgkmcnt(0)" ::: "memory");
    __builtin_amdgcn_sched_barrier(0);
    short8 pa[2][2], vb[4][2];
    #pragma unroll
    for (int mf = 0; mf < 2; ++mf)
      #pragma unroll
      for (int ks = 0; ks < 2; ++ks)
        pa[mf][ks] = *(const short8*)(&Pw[(mf * 16 + l15) * 72 + l4 * 8 + ks * 32]);
    #pragma unroll
    for (int df = 0; df < 4; ++df)
      #pragma unroll
      for (int ks = 0; ks < 2; ++ks)
        vb[df][ks] = *(const short8*)(&Vs[(df * 16 + l15) * 72 + l4 * 8 + ks * 32]);
    #pragma unroll
    for (int mf = 0; mf < 2; ++mf)
      #pragma unroll
      for (int df = 0; df < 4; ++df)
        #pragma unroll
        for (int ks = 0; ks < 2; ++ks)
          O[mf][df] = __builtin_amdgcn_mfma_f32_16x16x32_bf16(pa[mf][ks], vb[df][ks], O[mf][df], 0, 0, 0);
    __syncthreads();
  }
  // epilogue: rows u, cols (x&15)*64+d of the final-GEMM input
  #pragma unroll
  for (int mf = 0; mf < 2; ++mf) {
    #pragma unroll
    for (int df = 0; df < 4; ++df) {
      #pragma unroll
      for (int r = 0; r < 4; ++r) {
        int t = t0 + wid * 32 + mf * 16 + l4 * 4 + r;
        int col = h * 64 + df * 16 + l15;
        float o = O[mf][df][r] / l_[mf][r];
        at[((size_t)(t * 4 + b)) * 1024 + col] = f2bf(o);
      }
    }
  }
}

// ---------------- output projection GEMM ------------------------------------
__global__ __launch_bounds__(256, 2) void k_out_gemm(const u16* __restrict__ at, const u16* __restrict__ wt3,
                                                     const float* __restrict__ obias, float* __restrict__ out) {
  __shared__ u16 lds[8192];
  f32x4 acc[4][4];
  #pragma unroll
  for (int i = 0; i < 4; ++i)
    #pragma unroll
    for (int j = 0; j < 4; ++j) acc[i][j] = (f32x4){0.f, 0.f, 0.f, 0.f};
  const int m0 = blockIdx.y * 128, n0 = blockIdx.x * 128;
  gemm_tile(at, wt3, m0, n0, lds, lds + 4096, acc);
  const int lane = threadIdx.x & 63, wid = threadIdx.x >> 6;
  const int wm = wid >> 1, wn = wid & 1, l15 = lane & 15, l4 = lane >> 4;
  #pragma unroll
  for (int ni = 0; ni < 4; ++ni) {
    int col = n0 + wn * 64 + ni * 16 + l15;
    float bv = obias[col];
    #pragma unroll
    for (int mi = 0; mi < 4; ++mi) {
      #pragma unroll
      for (int r = 0; r < 4; ++r) {
        int row = m0 + wm * 64 + mi * 16 + l4 * 4 + r;
        out[(size_t)row * 1024 + col] = acc[mi][ni][r] + bv;
      }
    }
  }
}

extern "C" void kernel_launch(void* const* d_in, const int* in_sizes, int n_in,
                              void* d_out, int out_size, void* d_ws, size_t ws_size,
                              hipStream_t stream) {
  const float* query   = (const float*)d_in[0];
  const float* q_w     = (const float*)d_in[1];
  const float* q_b     = (const float*)d_in[2];
  const float* k_w     = (const float*)d_in[3];
  const float* k_b     = (const float*)d_in[4];
  const float* v_w     = (const float*)d_in[5];
  const float* v_b     = (const float*)d_in[6];
  const float* out_w   = (const float*)d_in[7];
  const float* out_b   = (const float*)d_in[8];
  const float* rel_emb = (const float*)d_in[9];
  const float* grep_w  = (const float*)d_in[10];
  const float* grep_b  = (const float*)d_in[11];
  const float* grep_a  = (const float*)d_in[12];
  const float* bias_k  = (const float*)d_in[13];
  const float* bias_v  = (const float*)d_in[14];
  char* ws = (char*)d_ws;
  u16*   qx  = (u16*)(ws + OFF_QX);
  u16*   wt  = (u16*)(ws + OFF_WT);
  u16*   qb  = (u16*)(ws + OFF_QB);
  u16*   kb  = (u16*)(ws + OFF_KB);
  u16*   vt  = (u16*)(ws + OFF_VT);
  u16*   at  = (u16*)(ws + OFF_AT);
  float* gate = (float*)(ws + OFF_GATE);
  float* pbt  = (float*)(ws + OFF_PB);
  float* out  = (float*)d_out;

  k_convert_q<<<dim3(4096), dim3(256), 0, stream>>>(query, qx);
  k_transw<<<dim3(32, 32, 4), dim3(32, 8), 0, stream>>>(q_w, k_w, v_w, out_w, wt);
  k_pb<<<dim3(8), dim3(256), 0, stream>>>(rel_emb, pbt);
  k_qkv_gemm<<<dim3(8, 32, 3), dim3(256), 0, stream>>>(qx, wt, q_b, k_b, v_b, qb, kb, vt);
  k_biaskv<<<dim3(16), dim3(256), 0, stream>>>(bias_k, bias_v, kb, vt);
  k_gate<<<dim3(16384), dim3(256), 0, stream>>>(qb, grep_w, grep_b, grep_a, gate);
  k_attn<<<dim3(8, 64), dim3(256), 0, stream>>>(qb, kb, vt, gate, pbt, at);
  k_out_gemm<<<dim3(8, 32), dim3(256), 0, stream>>>(at, wt + (size_t)3 * EMB * EMB, out_b, out);
}

// Round 2
// 249.158 us; speedup vs baseline: 1.0287x; 1.0287x over previous
//
#include <hip/hip_runtime.h>
#include <stdint.h>

typedef unsigned short u16;
typedef __attribute__((ext_vector_type(4))) float  f32x4;
typedef __attribute__((ext_vector_type(8))) short  short8;
typedef __attribute__((ext_vector_type(8))) u16    u16x8;
typedef __attribute__((ext_vector_type(4))) u16    u16x4;
typedef __attribute__((ext_vector_type(4))) float  fv4;

#define T_LEN 1024
#define EMB   1024
#define SPAD  1088   // padded src len (17*64), valid 0..1024
#define LOG2E 1.44269504f

// workspace offsets (bytes)
#define OFF_QX   (0ull)          // bf16 query    [4096][1024]          8 MB
#define OFF_WT   (8388608ull)    // bf16 W^T x4   [4][1024][1024]       8 MB
#define OFF_QB   (16777216ull)   // bf16 q_r      [64][1024][64]        8 MB
#define OFF_KB   (25165824ull)   // bf16 k_r      [64][1088][64]        8.5 MB
#define OFF_VT   (34078720ull)   // bf16 v_r^T    [64][64][1088]        8.5 MB
#define OFF_AT   (42991616ull)   // bf16 attn     [4096][1024]          8 MB (aux borrows head: written by k_pb, read by k_gate, then overwritten by k_attn)
#define OFF_GATE (51380224ull)   // f32 gate      [64][1024]
#define OFF_PB   (51642368ull)   // f32 pb table  [16][2048] (pre-scaled by log2e)

__device__ __forceinline__ u16 f2bf(float f) {
  uint32_t u = __builtin_bit_cast(uint32_t, f);
  u += 0x7FFFu + ((u >> 16) & 1u);
  return (u16)(u >> 16);
}
__device__ __forceinline__ float bf2f(u16 s) {
  uint32_t u = ((uint32_t)s) << 16;
  return __builtin_bit_cast(float, u);
}
__device__ __forceinline__ void gld_lds16(const void* gp, void* lp) {
  __builtin_amdgcn_global_load_lds(
      (const __attribute__((address_space(1))) uint32_t*)(uintptr_t)(gp),
      (__attribute__((address_space(3))) uint32_t*)(uintptr_t)(lp),
      16, 0, 0);
}

// ---------------- query f32 -> bf16 (straight copy-convert) ----------------
__global__ void k_convert_q(const float* __restrict__ q, u16* __restrict__ qx) {
  int i = blockIdx.x * 256 + threadIdx.x;
  fv4 v = *((const fv4*)q + i);
  u16x4 o = { f2bf(v[0]), f2bf(v[1]), f2bf(v[2]), f2bf(v[3]) };
  *((u16x4*)qx + i) = o;
}

// ---------------- weight transpose + convert: wt[z][n][k] = w_z[k][n] -------
__global__ void k_transw(const float* __restrict__ w0, const float* __restrict__ w1,
                         const float* __restrict__ w2, const float* __restrict__ w3,
                         u16* __restrict__ wt) {
  __shared__ float tile[32][33];
  const int z = blockIdx.z;
  const float* w = (z == 0) ? w0 : (z == 1) ? w1 : (z == 2) ? w2 : w3;
  const int r0 = blockIdx.y * 32, c0 = blockIdx.x * 32;
  const int tx = threadIdx.x, ty = threadIdx.y;
  #pragma unroll
  for (int j = 0; j < 32; j += 8)
    tile[ty + j][tx] = w[(size_t)(r0 + ty + j) * EMB + c0 + tx];
  __syncthreads();
  u16* o = wt + (size_t)z * EMB * EMB;
  #pragma unroll
  for (int j = 0; j < 32; j += 8)
    o[(size_t)(c0 + ty + j) * EMB + r0 + tx] = f2bf(tile[tx][ty + j]);
}

// ---------------- T5 bucket -> bias table (pre-scaled by log2e) + gate aux --
__global__ void k_pb(const float* __restrict__ rel_emb, float* __restrict__ pbtab,
                     const float* __restrict__ grep_w, const float* __restrict__ grep_b,
                     float* __restrict__ aux) {
  int i = blockIdx.x * 256 + threadIdx.x;   // 0..2047
  int rel = i - 1023;                       // u_k - u_q
  int bucket = (rel > 0) ? 16 : 0;
  int r = rel < 0 ? -rel : rel;
  int bidx;
  if (r < 8) bidx = r;
  else {
    float lf = __logf((float)r / 8.0f + 1e-6f) * (1.0f / logf(16.0f)) * 8.0f;
    int large = 8 + (int)lf;
    bidx = large < 15 ? large : 15;
  }
  bucket += bidx;
  #pragma unroll
  for (int h = 0; h < 16; ++h) pbtab[h * 2048 + i] = rel_emb[bucket * 16 + h] * LOG2E;
  if (blockIdx.x == 0) {
    if (threadIdx.x < 64) {
      float s = 0.f;
      #pragma unroll
      for (int j = 0; j < 8; ++j) s += grep_w[threadIdx.x * 8 + j];
      aux[threadIdx.x] = s;
    } else if (threadIdx.x == 64) {
      float s = 0.f;
      #pragma unroll
      for (int j = 0; j < 8; ++j) s += grep_b[j];
      aux[64] = s;
    }
  }
}

// ---------------- m97-style 128x128 bf16 GEMM core (B^T input) --------------
__device__ __forceinline__ void gemm_tile(const u16* __restrict__ A, const u16* __restrict__ Bt,
                                          int m0, int n0, u16* As, u16* Bs, f32x4 acc[4][4]) {
  const int tid = threadIdx.x;
  const int lane = tid & 63, wid = tid >> 6;
  const int wm = wid >> 1, wn = wid & 1;
  const int l15 = lane & 15, l4 = lane >> 4;
  for (int kt = 0; kt < EMB; kt += 32) {
    #pragma unroll
    for (int i = 0; i < 2; ++i) {
      int cw = wid * 64 + i * 256;   // wave-uniform chunk base
      int c = cw + lane;
      int row = c >> 2, cb = c & 3;
      gld_lds16(A  + (size_t)(m0 + row) * EMB + kt + cb * 8, (char*)As + (size_t)cw * 16);
      gld_lds16(Bt + (size_t)(n0 + row) * EMB + kt + cb * 8, (char*)Bs + (size_t)cw * 16);
    }
    __syncthreads();
    short8 a[4], b[4];
    #pragma unroll
    for (int f = 0; f < 4; ++f) {
      a[f] = *(const short8*)(As + (wm * 64 + f * 16 + l15) * 32 + l4 * 8);
      b[f] = *(const short8*)(Bs + (wn * 64 + f * 16 + l15) * 32 + l4 * 8);
    }
    #pragma unroll
    for (int mi = 0; mi < 4; ++mi)
      #pragma unroll
      for (int ni = 0; ni < 4; ++ni)
        acc[mi][ni] = __builtin_amdgcn_mfma_f32_16x16x32_bf16(a[mi], b[ni], acc[mi][ni], 0, 0, 0);
    __syncthreads();
  }
}

// ---------------- QKV projection GEMM with scrambled-scatter epilogue -------
__global__ __launch_bounds__(256, 2) void k_qkv_gemm(const u16* __restrict__ qx, const u16* __restrict__ wt,
    const float* __restrict__ qbias, const float* __restrict__ kbias, const float* __restrict__ vbias,
    u16* __restrict__ qb, u16* __restrict__ kb, u16* __restrict__ vt) {
  __shared__ u16 lds[8192];
  const int z = blockIdx.z;
  f32x4 acc[4][4];
  #pragma unroll
  for (int i = 0; i < 4; ++i)
    #pragma unroll
    for (int j = 0; j < 4; ++j) acc[i][j] = (f32x4){0.f, 0.f, 0.f, 0.f};
  const int m0 = blockIdx.y * 128, n0 = blockIdx.x * 128;
  gemm_tile(qx, wt + (size_t)z * EMB * EMB, m0, n0, lds, lds + 4096, acc);
  const float* bias = (z == 0) ? qbias : (z == 1) ? kbias : vbias;
  const int lane = threadIdx.x & 63, wid = threadIdx.x >> 6;
  const int wm = wid >> 1, wn = wid & 1, l15 = lane & 15, l4 = lane >> 4;
  #pragma unroll
  for (int ni = 0; ni < 4; ++ni) {
    int col = n0 + wn * 64 + ni * 16 + l15;
    float bv = bias[col];
    int h = col >> 6, d = col & 63;
    #pragma unroll
    for (int mi = 0; mi < 4; ++mi) {
      #pragma unroll
      for (int r = 0; r < 4; ++r) {
        int row = m0 + wm * 64 + mi * 16 + l4 * 4 + r;
        int t = row >> 2, b = row & 3;     // input rows are (t,b) interleaved
        float v = acc[mi][ni][r] + bv;
        if (z == 0) {
          // fairseq reshape (len=1024): x = b*16 + t>>6, u = (t&63)*16 + h
          int x = b * 16 + (t >> 6), u = ((t & 63) << 4) + h;
          qb[((size_t)x * 1024 + u) * 64 + d] = f2bf(v * (LOG2E / 256.0f)); // *scaling/ALPHA*log2e
        } else {
          // len=1025 scramble: w = s*16+h; x = b*16 + w/1025; u = w%1025
          int w = t * 16 + h;
          int j = w / 1025;
          int u = w - j * 1025;
          int x = b * 16 + j;
          if (z == 1) kb[((size_t)x * SPAD + u) * 64 + d] = f2bf(v);
          else        vt[((size_t)x * 64 + d) * SPAD + u] = f2bf(v);
        }
      }
    }
  }
}

// ---------------- bias_k / bias_v rows (land only in j=15 slots) ------------
__global__ void k_biaskv(const float* __restrict__ bias_k, const float* __restrict__ bias_v,
                         u16* __restrict__ kb, u16* __restrict__ vt) {
  int i = blockIdx.x * 256 + threadIdx.x;  // 0..4095
  int b = i >> 10, h = (i >> 6) & 15, d = i & 63;
  int x = b * 16 + 15, u = 1009 + h;       // w = 16384+h -> j=15, u=1009+h
  kb[((size_t)x * SPAD + u) * 64 + d] = f2bf(bias_k[h * 64 + d]);
  vt[((size_t)x * 64 + d) * SPAD + u] = f2bf(bias_v[h * 64 + d]);
}

// ---------------- gate[x][u] = sigmoid(q_row . wsum + bg) * grep_a[x&15] ----
// 8 rows per wave, 8 lanes per row, 16B coalesced loads
__global__ void k_gate(const u16* __restrict__ qb, const float* __restrict__ aux,
                       const float* __restrict__ grep_a, float* __restrict__ gate) {
  int tid = threadIdx.x, lane = tid & 63, wid = tid >> 6;
  int row0 = (blockIdx.x * 4 + wid) * 8;
  int sub = lane >> 3, d0 = (lane & 7) * 8;
  int item = row0 + sub;
  u16x8 q8 = *(const u16x8*)(qb + (size_t)item * 64 + d0);
  float acc = 0.f;
  #pragma unroll
  for (int j = 0; j < 8; ++j) acc += bf2f(q8[j]) * aux[d0 + j];
  acc += __shfl_xor(acc, 1);
  acc += __shfl_xor(acc, 2);
  acc += __shfl_xor(acc, 4);
  if ((lane & 7) == 0) {
    float v = acc * (256.0f / LOG2E) + aux[64];  // undo q pre-scale
    float s = 1.0f / (1.0f + __expf(-v));
    gate[item] = s * grep_a[(item >> 10) & 15];
  }
}

// ---------------- fused flash attention over scrambled (x,u) axes -----------
// 512 threads (8 waves x 16 rows), 128-row t-tile, Q LDS reused as P buffer.
__global__ __launch_bounds__(512, 4) void k_attn(const u16* __restrict__ qb, const u16* __restrict__ kb,
    const u16* __restrict__ vt, const float* __restrict__ gate, const float* __restrict__ pbt,
    u16* __restrict__ at) {
  __shared__ float pb_s[2048];
  __shared__ u16 Qs[128 * 72];   // Q preamble, then per-wave P buffers
  __shared__ u16 Ks[64 * 72];
  __shared__ u16 Vs[64 * 72];
  const int tid = threadIdx.x, lane = tid & 63, wid = tid >> 6;
  const int l15 = lane & 15, l4 = lane >> 4;
  // XCD swizzle: all 8 t-blocks of one x land on the same XCD (bid%8 == x%8)
  const int bid = blockIdx.x;
  const int x = (bid & 7) + ((bid >> 6) << 3);
  const int tblk = (bid >> 3) & 7;
  const int h = x & 15, b = x >> 4;
  const int t0 = tblk * 128;

  *(fv4*)(pb_s + tid * 4) = *(const fv4*)(pbt + (size_t)h * 2048 + tid * 4);
  #pragma unroll
  for (int i = 0; i < 2; ++i) {
    int c = tid + i * 512, row = c >> 3, cb = c & 7;
    *(u16x8*)(&Qs[row * 72 + cb * 8]) =
        *(const u16x8*)(qb + ((size_t)x * 1024 + t0 + row) * 64 + cb * 8);
  }
  const int trow = t0 + wid * 16 + l4 * 4;
  float g[4];
  #pragma unroll
  for (int r = 0; r < 4; ++r)
    g[r] = gate[(size_t)x * 1024 + trow + r];

  float m_[4], l_[4];
  f32x4 O[4];
  #pragma unroll
  for (int r = 0; r < 4; ++r) { m_[r] = -1e30f; l_[r] = 0.f; }
  #pragma unroll
  for (int df = 0; df < 4; ++df) O[df] = (f32x4){0.f, 0.f, 0.f, 0.f};

  __syncthreads();

  short8 qa[2];
  #pragma unroll
  for (int ks = 0; ks < 2; ++ks)
    qa[ks] = *(const short8*)(&Qs[(wid * 16 + l15) * 72 + ks * 32 + l4 * 8]);
  u16* Pw = &Qs[wid * 16 * 72];   // wave-private 16x64 P tile (reuses Q rows)

  for (int ic = 0; ic < 16; ++ic) {   // all 16 full chunks: no masking needed
    const int s0 = ic * 64;
    {
      int row = tid >> 3, cb = tid & 7;
      *(u16x8*)(&Ks[row * 72 + cb * 8]) =
          *(const u16x8*)(kb + ((size_t)x * SPAD + s0 + row) * 64 + cb * 8);
      *(u16x8*)(&Vs[row * 72 + cb * 8]) =
          *(const u16x8*)(vt + ((size_t)x * 64 + row) * SPAD + s0 + cb * 8);
    }
    __syncthreads();
    f32x4 sc[4];
    #pragma unroll
    for (int nf = 0; nf < 4; ++nf) {
      sc[nf] = (f32x4){0.f, 0.f, 0.f, 0.f};
      short8 k0 = *(const short8*)(&Ks[(nf * 16 + l15) * 72 + l4 * 8]);
      short8 k1 = *(const short8*)(&Ks[(nf * 16 + l15) * 72 + 32 + l4 * 8]);
      sc[nf] = __builtin_amdgcn_mfma_f32_16x16x32_bf16(qa[0], k0, sc[nf], 0, 0, 0);
      sc[nf] = __builtin_amdgcn_mfma_f32_16x16x32_bf16(qa[1], k1, sc[nf], 0, 0, 0);
    }
    // position bias (log2 domain), no mask: s <= 1023 always valid
    #pragma unroll
    for (int nf = 0; nf < 4; ++nf) {
      int s = s0 + nf * 16 + l15;
      #pragma unroll
      for (int r = 0; r < 4; ++r) {
        int ridx = s - (trow + r) + 1023;
        sc[nf][r] = sc[nf][r] + g[r] * pb_s[ridx];
      }
    }
    // online softmax (base-2), row spread across 16 lanes
    #pragma unroll
    for (int r = 0; r < 4; ++r) {
      float rm = fmaxf(fmaxf(sc[0][r], sc[1][r]), fmaxf(sc[2][r], sc[3][r]));
      rm = fmaxf(rm, __shfl_xor(rm, 1));
      rm = fmaxf(rm, __shfl_xor(rm, 2));
      rm = fmaxf(rm, __shfl_xor(rm, 4));
      rm = fmaxf(rm, __shfl_xor(rm, 8));
      float mo = m_[r];
      float mn = fmaxf(mo, rm);
      float cf = exp2f(mo - mn);
      m_[r] = mn;
      float rs = 0.f;
      #pragma unroll
      for (int nf = 0; nf < 4; ++nf) {
        float p = exp2f(sc[nf][r] - mn);
        sc[nf][r] = p;
        rs += p;
      }
      rs += __shfl_xor(rs, 1);
      rs += __shfl_xor(rs, 2);
      rs += __shfl_xor(rs, 4);
      rs += __shfl_xor(rs, 8);
      l_[r] = l_[r] * cf + rs;
      #pragma unroll
      for (int df = 0; df < 4; ++df) O[df][r] *= cf;
    }
    // P (C/D layout) -> wave-private LDS -> A-fragment layout
    #pragma unroll
    for (int nf = 0; nf < 4; ++nf)
      #pragma unroll
      for (int r = 0; r < 4; ++r)
        Pw[(l4 * 4 + r) * 72 + nf * 16 + l15] = f2bf(sc[nf][r]);
    __asm__ volatile("s_waitcnt lgkmcnt(0)" ::: "memory");
    __builtin_amdgcn_sched_barrier(0);
    short8 pa[2];
    #pragma unroll
    for (int ks = 0; ks < 2; ++ks)
      pa[ks] = *(const short8*)(&Pw[l15 * 72 + ks * 32 + l4 * 8]);
    #pragma unroll
    for (int df = 0; df < 4; ++df) {
      short8 v0 = *(const short8*)(&Vs[(df * 16 + l15) * 72 + l4 * 8]);
      short8 v1 = *(const short8*)(&Vs[(df * 16 + l15) * 72 + 32 + l4 * 8]);
      O[df] = __builtin_amdgcn_mfma_f32_16x16x32_bf16(pa[0], v0, O[df], 0, 0, 0);
      O[df] = __builtin_amdgcn_mfma_f32_16x16x32_bf16(pa[1], v1, O[df], 0, 0, 0);
    }
    __syncthreads();
  }

  // ---- tail: the single extra column s = 1024 (bias_kv row) ----
  if (tid < 128) {
    int row = tid >> 3, cb = tid & 7;
    *(u16x8*)(&Ks[row * 72 + cb * 8]) =
        *(const u16x8*)(kb + ((size_t)x * SPAD + 1024 + row) * 64 + cb * 8);
  }
  __syncthreads();
  f32x4 sc0 = (f32x4){0.f, 0.f, 0.f, 0.f};
  {
    short8 k0 = *(const short8*)(&Ks[l15 * 72 + l4 * 8]);
    short8 k1 = *(const short8*)(&Ks[l15 * 72 + 32 + l4 * 8]);
    sc0 = __builtin_amdgcn_mfma_f32_16x16x32_bf16(qa[0], k0, sc0, 0, 0, 0);
    sc0 = __builtin_amdgcn_mfma_f32_16x16x32_bf16(qa[1], k1, sc0, 0, 0, 0);
  }
  float vtail[4];
  #pragma unroll
  for (int df = 0; df < 4; ++df)
    vtail[df] = bf2f(vt[((size_t)x * 64 + df * 16 + l15) * SPAD + 1024]);
  #pragma unroll
  for (int r = 0; r < 4; ++r) {
    int t = trow + r;
    float dotv = __shfl(sc0[r], lane & 48);      // col 0 of this row group
    float se = dotv + g[r] * pb_s[2047 - t];
    float mn = fmaxf(m_[r], se);
    float cf = exp2f(m_[r] - mn);
    float pe = exp2f(se - mn);
    l_[r] = l_[r] * cf + pe;
    #pragma unroll
    for (int df = 0; df < 4; ++df) O[df][r] = O[df][r] * cf + pe * vtail[df];
  }

  // epilogue: rows u, cols (x&15)*64+d of the final-GEMM input
  #pragma unroll
  for (int df = 0; df < 4; ++df) {
    #pragma unroll
    for (int r = 0; r < 4; ++r) {
      int t = trow + r;
      int col = h * 64 + df * 16 + l15;
      at[((size_t)(t * 4 + b)) * 1024 + col] = f2bf(O[df][r] / l_[r]);
    }
  }
}

// ---------------- output projection GEMM ------------------------------------
__global__ __launch_bounds__(256, 2) void k_out_gemm(const u16* __restrict__ at, const u16* __restrict__ wt3,
                                                     const float* __restrict__ obias, float* __restrict__ out) {
  __shared__ u16 lds[8192];
  f32x4 acc[4][4];
  #pragma unroll
  for (int i = 0; i < 4; ++i)
    #pragma unroll
    for (int j = 0; j < 4; ++j) acc[i][j] = (f32x4){0.f, 0.f, 0.f, 0.f};
  const int m0 = blockIdx.y * 128, n0 = blockIdx.x * 128;
  gemm_tile(at, wt3, m0, n0, lds, lds + 4096, acc);
  const int lane = threadIdx.x & 63, wid = threadIdx.x >> 6;
  const int wm = wid >> 1, wn = wid & 1, l15 = lane & 15, l4 = lane >> 4;
  #pragma unroll
  for (int ni = 0; ni < 4; ++ni) {
    int col = n0 + wn * 64 + ni * 16 + l15;
    float bv = obias[col];
    #pragma unroll
    for (int mi = 0; mi < 4; ++mi) {
      #pragma unroll
      for (int r = 0; r < 4; ++r) {
        int row = m0 + wm * 64 + mi * 16 + l4 * 4 + r;
        out[(size_t)row * 1024 + col] = acc[mi][ni][r] + bv;
      }
    }
  }
}

extern "C" void kernel_launch(void* const* d_in, const int* in_sizes, int n_in,
                              void* d_out, int out_size, void* d_ws, size_t ws_size,
                              hipStream_t stream) {
  const float* query   = (const float*)d_in[0];
  const float* q_w     = (const float*)d_in[1];
  const float* q_b     = (const float*)d_in[2];
  const float* k_w     = (const float*)d_in[3];
  const float* k_b     = (const float*)d_in[4];
  const float* v_w     = (const float*)d_in[5];
  const float* v_b     = (const float*)d_in[6];
  const float* out_w   = (const float*)d_in[7];
  const float* out_b   = (const float*)d_in[8];
  const float* rel_emb = (const float*)d_in[9];
  const float* grep_w  = (const float*)d_in[10];
  const float* grep_b  = (const float*)d_in[11];
  const float* grep_a  = (const float*)d_in[12];
  const float* bias_k  = (const float*)d_in[13];
  const float* bias_v  = (const float*)d_in[14];
  char* ws = (char*)d_ws;
  u16*   qx  = (u16*)(ws + OFF_QX);
  u16*   wt  = (u16*)(ws + OFF_WT);
  u16*   qb  = (u16*)(ws + OFF_QB);
  u16*   kb  = (u16*)(ws + OFF_KB);
  u16*   vt  = (u16*)(ws + OFF_VT);
  u16*   at  = (u16*)(ws + OFF_AT);
  float* aux = (float*)(ws + OFF_AT);   // borrowed: pb writes, gate reads, attn later overwrites
  float* gate = (float*)(ws + OFF_GATE);
  float* pbt  = (float*)(ws + OFF_PB);
  float* out  = (float*)d_out;

  k_convert_q<<<dim3(4096), dim3(256), 0, stream>>>(query, qx);
  k_transw<<<dim3(32, 32, 4), dim3(32, 8), 0, stream>>>(q_w, k_w, v_w, out_w, wt);
  k_pb<<<dim3(8), dim3(256), 0, stream>>>(rel_emb, pbt, grep_w, grep_b, aux);
  k_qkv_gemm<<<dim3(8, 32, 3), dim3(256), 0, stream>>>(qx, wt, q_b, k_b, v_b, qb, kb, vt);
  k_biaskv<<<dim3(16), dim3(256), 0, stream>>>(bias_k, bias_v, kb, vt);
  k_gate<<<dim3(2048), dim3(256), 0, stream>>>(qb, aux, grep_a, gate);
  k_attn<<<dim3(512), dim3(512), 0, stream>>>(qb, kb, vt, gate, pbt, at);
  k_out_gemm<<<dim3(8, 32), dim3(256), 0, stream>>>(at, wt + (size_t)3 * EMB * EMB, out_b, out);
}

// Round 3
// 226.473 us; speedup vs baseline: 1.1317x; 1.1002x over previous
//
#include <hip/hip_runtime.h>
#include <stdint.h>

typedef unsigned short u16;
typedef __attribute__((ext_vector_type(4))) float  f32x4;
typedef __attribute__((ext_vector_type(8))) short  short8;
typedef __attribute__((ext_vector_type(8))) u16    u16x8;
typedef __attribute__((ext_vector_type(4))) u16    u16x4;
typedef __attribute__((ext_vector_type(4))) float  fv4;

#define T_LEN 1024
#define EMB   1024
#define SPAD  1088   // padded src len (17*64), valid 0..1024
#define LOG2E 1.44269504f

// workspace offsets (bytes)
#define OFF_QX   (0ull)          // bf16 query    [4096][1024]          8 MB
#define OFF_WT   (8388608ull)    // bf16 W^T x4   [4][1024][1024]       8 MB
#define OFF_QB   (16777216ull)   // bf16 q_r      [64][1024][64]        8 MB
#define OFF_KB   (25165824ull)   // bf16 k_r      [64][1088][64]        8.5 MB
#define OFF_VT   (34078720ull)   // bf16 v_r^T    [64][64][1088]        8.5 MB
#define OFF_AT   (42991616ull)   // bf16 attn     [4096][1024]          8 MB (aux borrows head)
#define OFF_GATE (51380224ull)   // f32 gate      [64][1024]
#define OFF_PB   (51642368ull)   // f32 pb table  [16][2048] REVERSED: idx = 1024 + t - s, pre-scaled log2e

__device__ __forceinline__ u16 f2bf(float f) {
  uint32_t u = __builtin_bit_cast(uint32_t, f);
  u += 0x7FFFu + ((u >> 16) & 1u);
  return (u16)(u >> 16);
}
__device__ __forceinline__ float bf2f(u16 s) {
  uint32_t u = ((uint32_t)s) << 16;
  return __builtin_bit_cast(float, u);
}
__device__ __forceinline__ void gld_lds16(const void* gp, void* lp) {
  __builtin_amdgcn_global_load_lds(
      (const __attribute__((address_space(1))) uint32_t*)(uintptr_t)(gp),
      (__attribute__((address_space(3))) uint32_t*)(uintptr_t)(lp),
      16, 0, 0);
}

// ---------------- query f32 -> bf16 ----------------
__global__ void k_convert_q(const float* __restrict__ q, u16* __restrict__ qx) {
  int i = blockIdx.x * 256 + threadIdx.x;
  fv4 v = *((const fv4*)q + i);
  u16x4 o = { f2bf(v[0]), f2bf(v[1]), f2bf(v[2]), f2bf(v[3]) };
  *((u16x4*)qx + i) = o;
}

// ---------------- weight transpose + convert: wt[z][n][k] = w_z[k][n] -------
__global__ void k_transw(const float* __restrict__ w0, const float* __restrict__ w1,
                         const float* __restrict__ w2, const float* __restrict__ w3,
                         u16* __restrict__ wt) {
  __shared__ float tile[32][33];
  const int z = blockIdx.z;
  const float* w = (z == 0) ? w0 : (z == 1) ? w1 : (z == 2) ? w2 : w3;
  const int r0 = blockIdx.y * 32, c0 = blockIdx.x * 32;
  const int tx = threadIdx.x, ty = threadIdx.y;
  #pragma unroll
  for (int j = 0; j < 32; j += 8)
    tile[ty + j][tx] = w[(size_t)(r0 + ty + j) * EMB + c0 + tx];
  __syncthreads();
  u16* o = wt + (size_t)z * EMB * EMB;
  #pragma unroll
  for (int j = 0; j < 32; j += 8)
    o[(size_t)(c0 + ty + j) * EMB + r0 + tx] = f2bf(tile[tx][ty + j]);
}

// ---------------- T5 bucket -> REVERSED bias table + gate aux ---------------
// pbtab[h][i] = pb(rel = 1024 - i) * log2e   (i = 1024 + t - s)
__global__ void k_pb(const float* __restrict__ rel_emb, float* __restrict__ pbtab,
                     const float* __restrict__ grep_w, const float* __restrict__ grep_b,
                     float* __restrict__ aux) {
  int i = blockIdx.x * 256 + threadIdx.x;   // 0..2047
  int rel = 1024 - i;                       // s - t
  int bucket = (rel > 0) ? 16 : 0;
  int r = rel < 0 ? -rel : rel;
  int bidx;
  if (r < 8) bidx = r;
  else {
    float lf = __logf((float)r / 8.0f + 1e-6f) * (1.0f / logf(16.0f)) * 8.0f;
    int large = 8 + (int)lf;
    bidx = large < 15 ? large : 15;
  }
  bucket += bidx;
  #pragma unroll
  for (int h = 0; h < 16; ++h) pbtab[h * 2048 + i] = rel_emb[bucket * 16 + h] * LOG2E;
  if (blockIdx.x == 0) {
    if (threadIdx.x < 64) {
      float s = 0.f;
      #pragma unroll
      for (int j = 0; j < 8; ++j) s += grep_w[threadIdx.x * 8 + j];
      aux[threadIdx.x] = s;
    } else if (threadIdx.x == 64) {
      float s = 0.f;
      #pragma unroll
      for (int j = 0; j < 8; ++j) s += grep_b[j];
      aux[64] = s;
    }
  }
}

// ---------------- m97-style 128x128 bf16 GEMM core (B^T input) --------------
__device__ __forceinline__ void gemm_tile(const u16* __restrict__ A, const u16* __restrict__ Bt,
                                          int m0, int n0, u16* As, u16* Bs, f32x4 acc[4][4]) {
  const int tid = threadIdx.x;
  const int lane = tid & 63, wid = tid >> 6;
  const int wm = wid >> 1, wn = wid & 1;
  const int l15 = lane & 15, l4 = lane >> 4;
  for (int kt = 0; kt < EMB; kt += 32) {
    #pragma unroll
    for (int i = 0; i < 2; ++i) {
      int cw = wid * 64 + i * 256;   // wave-uniform chunk base
      int c = cw + lane;
      int row = c >> 2, cb = c & 3;
      gld_lds16(A  + (size_t)(m0 + row) * EMB + kt + cb * 8, (char*)As + (size_t)cw * 16);
      gld_lds16(Bt + (size_t)(n0 + row) * EMB + kt + cb * 8, (char*)Bs + (size_t)cw * 16);
    }
    __syncthreads();
    short8 a[4], b[4];
    #pragma unroll
    for (int f = 0; f < 4; ++f) {
      a[f] = *(const short8*)(As + (wm * 64 + f * 16 + l15) * 32 + l4 * 8);
      b[f] = *(const short8*)(Bs + (wn * 64 + f * 16 + l15) * 32 + l4 * 8);
    }
    #pragma unroll
    for (int mi = 0; mi < 4; ++mi)
      #pragma unroll
      for (int ni = 0; ni < 4; ++ni)
        acc[mi][ni] = __builtin_amdgcn_mfma_f32_16x16x32_bf16(a[mi], b[ni], acc[mi][ni], 0, 0, 0);
    __syncthreads();
  }
}

// ---------------- fused QKV projection GEMM (N = 3072), scrambled scatter ---
__global__ __launch_bounds__(256, 2) void k_qkv_gemm(const u16* __restrict__ qx, const u16* __restrict__ wt,
    const float* __restrict__ qbias, const float* __restrict__ kbias, const float* __restrict__ vbias,
    u16* __restrict__ qb, u16* __restrict__ kb, u16* __restrict__ vt) {
  __shared__ u16 lds[8192];
  f32x4 acc[4][4];
  #pragma unroll
  for (int i = 0; i < 4; ++i)
    #pragma unroll
    for (int j = 0; j < 4; ++j) acc[i][j] = (f32x4){0.f, 0.f, 0.f, 0.f};
  const int m0 = blockIdx.y * 128, n0g = blockIdx.x * 128;   // n0g in [0,3072)
  gemm_tile(qx, wt, m0, n0g, lds, lds + 4096, acc);          // wt is [3072][1024]
  const int z = n0g >> 10;
  const float* bias = (z == 0) ? qbias : (z == 1) ? kbias : vbias;
  const int lane = threadIdx.x & 63, wid = threadIdx.x >> 6;
  const int wm = wid >> 1, wn = wid & 1, l15 = lane & 15, l4 = lane >> 4;
  #pragma unroll
  for (int ni = 0; ni < 4; ++ni) {
    int colg = n0g + wn * 64 + ni * 16 + l15;
    int col = colg & 1023;
    float bv = bias[col];
    int h = col >> 6, d = col & 63;
    #pragma unroll
    for (int mi = 0; mi < 4; ++mi) {
      #pragma unroll
      for (int r = 0; r < 4; ++r) {
        int row = m0 + wm * 64 + mi * 16 + l4 * 4 + r;
        int t = row >> 2, b = row & 3;     // input rows are (t,b) interleaved
        float v = acc[mi][ni][r] + bv;
        if (z == 0) {
          int x = b * 16 + (t >> 6), u = ((t & 63) << 4) + h;
          qb[((size_t)x * 1024 + u) * 64 + d] = f2bf(v * (LOG2E / 256.0f));
        } else {
          int w = t * 16 + h;
          int j = w / 1025;
          int u = w - j * 1025;
          int x = b * 16 + j;
          if (z == 1) kb[((size_t)x * SPAD + u) * 64 + d] = f2bf(v);
          else        vt[((size_t)x * 64 + d) * SPAD + u] = f2bf(v);
        }
      }
    }
  }
}

// ---------------- bias_k / bias_v rows ------------
__global__ void k_biaskv(const float* __restrict__ bias_k, const float* __restrict__ bias_v,
                         u16* __restrict__ kb, u16* __restrict__ vt) {
  int i = blockIdx.x * 256 + threadIdx.x;  // 0..4095
  int b = i >> 10, h = (i >> 6) & 15, d = i & 63;
  int x = b * 16 + 15, u = 1009 + h;
  kb[((size_t)x * SPAD + u) * 64 + d] = f2bf(bias_k[h * 64 + d]);
  vt[((size_t)x * 64 + d) * SPAD + u] = f2bf(bias_v[h * 64 + d]);
}

// ---------------- gate --------------------------------------------------
__global__ void k_gate(const u16* __restrict__ qb, const float* __restrict__ aux,
                       const float* __restrict__ grep_a, float* __restrict__ gate) {
  int tid = threadIdx.x, lane = tid & 63, wid = tid >> 6;
  int row0 = (blockIdx.x * 4 + wid) * 8;
  int sub = lane >> 3, d0 = (lane & 7) * 8;
  int item = row0 + sub;
  u16x8 q8 = *(const u16x8*)(qb + (size_t)item * 64 + d0);
  float acc = 0.f;
  #pragma unroll
  for (int j = 0; j < 8; ++j) acc += bf2f(q8[j]) * aux[d0 + j];
  acc += __shfl_xor(acc, 1);
  acc += __shfl_xor(acc, 2);
  acc += __shfl_xor(acc, 4);
  if ((lane & 7) == 0) {
    float v = acc * (256.0f / LOG2E) + aux[64];
    float s = 1.0f / (1.0f + __expf(-v));
    gate[item] = s * grep_a[(item >> 10) & 15];
  }
}

// ---------------- fused flash attention v3 ----------------------------------
// 256 thr / 4 waves, 32 q-rows per wave, KVBLK=64, double-buffered swizzled LDS,
// fixed-max base-2 softmax (no max tracking, no rescale).
__global__ __launch_bounds__(256, 2) void k_attn(const u16* __restrict__ qb, const u16* __restrict__ kb,
    const u16* __restrict__ vt, const float* __restrict__ gate, const float* __restrict__ pbt,
    u16* __restrict__ at) {
  __shared__ float pb_s[2048];
  __shared__ u16 Ksh[2 * 4096];   // [buf][64 k][64 d] swizzled
  __shared__ u16 Vsh[2 * 4096];   // [buf][64 d][64 k] swizzled (V^T)
  __shared__ u16 Psh[4 * 2048];   // per-wave [32 q][64 k] swizzled
  const int tid = threadIdx.x, lane = tid & 63, wid = tid >> 6;
  const int l15 = lane & 15, l4 = lane >> 4;
  const int bid = blockIdx.x;
  const int x = (bid & 7) + ((bid >> 6) << 3);   // XCD swizzle
  const int tblk = (bid >> 3) & 7;
  const int h = x & 15, b = x >> 4;
  const int qrow0 = tblk * 128 + wid * 32;

  #pragma unroll
  for (int i = 0; i < 2; ++i) {
    int idx = (tid + i * 256) * 4;
    *(fv4*)(pb_s + idx) = *(const fv4*)(pbt + (size_t)h * 2048 + idx);
  }

  // Q fragments + gate in registers
  short8 qa[2][2];
  #pragma unroll
  for (int pf = 0; pf < 2; ++pf)
    #pragma unroll
    for (int ks = 0; ks < 2; ++ks)
      qa[pf][ks] = *(const short8*)(qb + ((size_t)x * 1024 + qrow0 + pf * 16 + l15) * 64 + ks * 32 + l4 * 8);
  float g[2][4];
  #pragma unroll
  for (int pf = 0; pf < 2; ++pf)
    #pragma unroll
    for (int r = 0; r < 4; ++r)
      g[pf][r] = gate[(size_t)x * 1024 + qrow0 + pf * 16 + l4 * 4 + r];

  // staging source pointers (pre-swizzled global addresses, linear LDS dest)
  const u16* kbx = kb + (size_t)x * SPAD * 64;
  const u16* vtx = vt + (size_t)x * 64 * SPAD;
  const int ra = tid >> 3, sa = tid & 7;          // rows 0..31
  const int rb = ra + 32;                          // rows 32..63
  const u16* sK0 = kbx + ra * 64 + ((sa * 8) ^ ((ra & 7) << 3));
  const u16* sK1 = kbx + rb * 64 + ((sa * 8) ^ ((rb & 7) << 3));
  const u16* sV0 = vtx + (size_t)ra * SPAD + ((sa * 8) ^ ((ra & 7) << 3));
  const u16* sV1 = vtx + (size_t)rb * SPAD + ((sa * 8) ^ ((rb & 7) << 3));

  // fragment read offsets (swizzled)
  const int swz = (l15 & 7) << 3;
  int kfO[4][2], vbO[4][2];
  #pragma unroll
  for (int f = 0; f < 4; ++f)
    #pragma unroll
    for (int ks = 0; ks < 2; ++ks) {
      kfO[f][ks] = (f * 16 + l15) * 64 + ((ks * 32 + l4 * 8) ^ swz);
      vbO[f][ks] = kfO[f][ks];
    }
  int paO[2][2];
  #pragma unroll
  for (int pf = 0; pf < 2; ++pf)
    #pragma unroll
    for (int ks = 0; ks < 2; ++ks)
      paO[pf][ks] = (pf * 16 + l15) * 64 + ((ks * 32 + l4 * 8) ^ swz);
  u16* Pw = Psh + wid * 2048;

  f32x4 O[2][4];
  float l_[2][4];
  #pragma unroll
  for (int pf = 0; pf < 2; ++pf) {
    #pragma unroll
    for (int df = 0; df < 4; ++df) O[pf][df] = (f32x4){0.f, 0.f, 0.f, 0.f};
    #pragma unroll
    for (int r = 0; r < 4; ++r) l_[pf][r] = 0.f;
  }

  // prologue: stage chunk 0 into buf 0
  gld_lds16(sK0, (char*)Ksh + wid * 1024);
  gld_lds16(sK1, (char*)Ksh + 4096 + wid * 1024);
  gld_lds16(sV0, (char*)Vsh + wid * 1024);
  gld_lds16(sV1, (char*)Vsh + 4096 + wid * 1024);
  sK0 += 4096; sK1 += 4096; sV0 += 64; sV1 += 64;
  __asm__ volatile("s_waitcnt vmcnt(0)" ::: "memory");
  __syncthreads();

  int cur = 0;
  for (int ic = 0; ic < 16; ++ic) {
    const int nxt = cur ^ 1;
    char* Kn = (char*)(Ksh + nxt * 4096);
    char* Vn = (char*)(Vsh + nxt * 4096);
    if (ic < 15) {
      gld_lds16(sK0, Kn + wid * 1024);
      gld_lds16(sK1, Kn + 4096 + wid * 1024);
      gld_lds16(sV0, Vn + wid * 1024);
      gld_lds16(sV1, Vn + 4096 + wid * 1024);
      sK0 += 4096; sK1 += 4096; sV0 += 64; sV1 += 64;
    } else if (wid < 2) {
      // stage K tail rows 1024..1039 linearly (only row 0 is real; rest garbage-safe)
      int ro = (wid * 64 + lane) >> 3, so = lane & 7;
      gld_lds16(kbx + (size_t)(1024 + ro) * 64 + so * 8, Kn + wid * 1024);
    }
    const u16* Kc = Ksh + cur * 4096;
    const u16* Vc = Vsh + cur * 4096;

    // QK^T
    f32x4 sc[2][4];
    #pragma unroll
    for (int pf = 0; pf < 2; ++pf)
      #pragma unroll
      for (int nf = 0; nf < 4; ++nf) sc[pf][nf] = (f32x4){0.f, 0.f, 0.f, 0.f};
    #pragma unroll
    for (int nf = 0; nf < 4; ++nf)
      #pragma unroll
      for (int ks = 0; ks < 2; ++ks) {
        short8 kf = *(const short8*)(Kc + kfO[nf][ks]);
        sc[0][nf] = __builtin_amdgcn_mfma_f32_16x16x32_bf16(qa[0][ks], kf, sc[0][nf], 0, 0, 0);
        sc[1][nf] = __builtin_amdgcn_mfma_f32_16x16x32_bf16(qa[1][ks], kf, sc[1][nf], 0, 0, 0);
      }

    // bias + exp2 (fixed max) + partial-l + P store (truncated bf16)
    #pragma unroll
    for (int pf = 0; pf < 2; ++pf)
      #pragma unroll
      for (int nf = 0; nf < 4; ++nf) {
        const int base = 1024 + qrow0 + pf * 16 + l4 * 4 - (ic * 64 + nf * 16 + l15);
        #pragma unroll
        for (int r = 0; r < 4; ++r) {
          float sv = sc[pf][nf][r] + g[pf][r] * pb_s[base + r];
          float p = exp2f(sv);
          l_[pf][r] += p;
          const int prow = pf * 16 + l4 * 4 + r;
          Pw[prow * 64 + ((nf * 16 + l15) ^ ((prow & 7) << 3))] =
              (u16)(__builtin_bit_cast(uint32_t, p) >> 16);
        }
      }
    __asm__ volatile("s_waitcnt lgkmcnt(0)" ::: "memory");
    __builtin_amdgcn_sched_barrier(0);

    // PV
    #pragma unroll
    for (int ks = 0; ks < 2; ++ks) {
      short8 pa0 = *(const short8*)(Pw + paO[0][ks]);
      short8 pa1 = *(const short8*)(Pw + paO[1][ks]);
      #pragma unroll
      for (int df = 0; df < 4; ++df) {
        short8 vb = *(const short8*)(Vc + vbO[df][ks]);
        O[0][df] = __builtin_amdgcn_mfma_f32_16x16x32_bf16(pa0, vb, O[0][df], 0, 0, 0);
        O[1][df] = __builtin_amdgcn_mfma_f32_16x16x32_bf16(pa1, vb, O[1][df], 0, 0, 0);
      }
    }
    __asm__ volatile("s_waitcnt vmcnt(0)" ::: "memory");
    __syncthreads();
    cur = nxt;
  }

  // ---- tail: s = 1024 ----
  const u16* Kt = Ksh + cur * 4096;
  short8 kt0 = *(const short8*)(Kt + l15 * 64 + l4 * 8);
  short8 kt1 = *(const short8*)(Kt + l15 * 64 + 32 + l4 * 8);
  f32x4 sc0[2];
  #pragma unroll
  for (int pf = 0; pf < 2; ++pf) {
    sc0[pf] = (f32x4){0.f, 0.f, 0.f, 0.f};
    sc0[pf] = __builtin_amdgcn_mfma_f32_16x16x32_bf16(qa[pf][0], kt0, sc0[pf], 0, 0, 0);
    sc0[pf] = __builtin_amdgcn_mfma_f32_16x16x32_bf16(qa[pf][1], kt1, sc0[pf], 0, 0, 0);
  }
  float vtail[4];
  #pragma unroll
  for (int df = 0; df < 4; ++df)
    vtail[df] = bf2f(vt[((size_t)x * 64 + df * 16 + l15) * SPAD + 1024]);

  float pt[2][4], linv[2][4];
  #pragma unroll
  for (int pf = 0; pf < 2; ++pf)
    #pragma unroll
    for (int r = 0; r < 4; ++r) {
      float dotv = __shfl(sc0[pf][r], lane & 48);      // col 0 (s=1024)
      int t = qrow0 + pf * 16 + l4 * 4 + r;
      float se = dotv + g[pf][r] * pb_s[t];            // idx = 1024 + t - 1024
      float p = exp2f(se);
      float ls = l_[pf][r];
      ls += __shfl_xor(ls, 1);
      ls += __shfl_xor(ls, 2);
      ls += __shfl_xor(ls, 4);
      ls += __shfl_xor(ls, 8);
      pt[pf][r] = p;
      linv[pf][r] = 1.0f / (ls + p);
    }

  #pragma unroll
  for (int pf = 0; pf < 2; ++pf)
    #pragma unroll
    for (int df = 0; df < 4; ++df)
      #pragma unroll
      for (int r = 0; r < 4; ++r) {
        int t = qrow0 + pf * 16 + l4 * 4 + r;
        float o = (O[pf][df][r] + pt[pf][r] * vtail[df]) * linv[pf][r];
        at[((size_t)(t * 4 + b)) * 1024 + h * 64 + df * 16 + l15] = f2bf(o);
      }
}

// ---------------- output projection GEMM ------------------------------------
__global__ __launch_bounds__(256, 2) void k_out_gemm(const u16* __restrict__ at, const u16* __restrict__ wt3,
                                                     const float* __restrict__ obias, float* __restrict__ out) {
  __shared__ u16 lds[8192];
  f32x4 acc[4][4];
  #pragma unroll
  for (int i = 0; i < 4; ++i)
    #pragma unroll
    for (int j = 0; j < 4; ++j) acc[i][j] = (f32x4){0.f, 0.f, 0.f, 0.f};
  const int m0 = blockIdx.y * 128, n0 = blockIdx.x * 128;
  gemm_tile(at, wt3, m0, n0, lds, lds + 4096, acc);
  const int lane = threadIdx.x & 63, wid = threadIdx.x >> 6;
  const int wm = wid >> 1, wn = wid & 1, l15 = lane & 15, l4 = lane >> 4;
  #pragma unroll
  for (int ni = 0; ni < 4; ++ni) {
    int col = n0 + wn * 64 + ni * 16 + l15;
    float bv = obias[col];
    #pragma unroll
    for (int mi = 0; mi < 4; ++mi) {
      #pragma unroll
      for (int r = 0; r < 4; ++r) {
        int row = m0 + wm * 64 + mi * 16 + l4 * 4 + r;
        out[(size_t)row * 1024 + col] = acc[mi][ni][r] + bv;
      }
    }
  }
}

extern "C" void kernel_launch(void* const* d_in, const int* in_sizes, int n_in,
                              void* d_out, int out_size, void* d_ws, size_t ws_size,
                              hipStream_t stream) {
  const float* query   = (const float*)d_in[0];
  const float* q_w     = (const float*)d_in[1];
  const float* q_b     = (const float*)d_in[2];
  const float* k_w     = (const float*)d_in[3];
  const float* k_b     = (const float*)d_in[4];
  const float* v_w     = (const float*)d_in[5];
  const float* v_b     = (const float*)d_in[6];
  const float* out_w   = (const float*)d_in[7];
  const float* out_b   = (const float*)d_in[8];
  const float* rel_emb = (const float*)d_in[9];
  const float* grep_w  = (const float*)d_in[10];
  const float* grep_b  = (const float*)d_in[11];
  const float* grep_a  = (const float*)d_in[12];
  const float* bias_k  = (const float*)d_in[13];
  const float* bias_v  = (const float*)d_in[14];
  char* ws = (char*)d_ws;
  u16*   qx  = (u16*)(ws + OFF_QX);
  u16*   wt  = (u16*)(ws + OFF_WT);
  u16*   qb  = (u16*)(ws + OFF_QB);
  u16*   kb  = (u16*)(ws + OFF_KB);
  u16*   vt  = (u16*)(ws + OFF_VT);
  u16*   at  = (u16*)(ws + OFF_AT);
  float* aux = (float*)(ws + OFF_AT);   // borrowed before k_attn overwrites
  float* gate = (float*)(ws + OFF_GATE);
  float* pbt  = (float*)(ws + OFF_PB);
  float* out  = (float*)d_out;

  k_convert_q<<<dim3(4096), dim3(256), 0, stream>>>(query, qx);
  k_transw<<<dim3(32, 32, 4), dim3(32, 8), 0, stream>>>(q_w, k_w, v_w, out_w, wt);
  k_pb<<<dim3(8), dim3(256), 0, stream>>>(rel_emb, pbt, grep_w, grep_b, aux);
  k_qkv_gemm<<<dim3(24, 32), dim3(256), 0, stream>>>(qx, wt, q_b, k_b, v_b, qb, kb, vt);
  k_biaskv<<<dim3(16), dim3(256), 0, stream>>>(bias_k, bias_v, kb, vt);
  k_gate<<<dim3(2048), dim3(256), 0, stream>>>(qb, aux, grep_a, gate);
  k_attn<<<dim3(512), dim3(256), 0, stream>>>(qb, kb, vt, gate, pbt, at);
  k_out_gemm<<<dim3(8, 32), dim3(256), 0, stream>>>(at, wt + (size_t)3 * EMB * EMB, out_b, out);
}

// Round 4
// 218.480 us; speedup vs baseline: 1.1731x; 1.0366x over previous
//
#include <hip/hip_runtime.h>
#include <stdint.h>

typedef unsigned short u16;
typedef __attribute__((ext_vector_type(4))) float  f32x4;
typedef __attribute__((ext_vector_type(8))) short  short8;
typedef __attribute__((ext_vector_type(8))) u16    u16x8;
typedef __attribute__((ext_vector_type(4))) u16    u16x4;
typedef __attribute__((ext_vector_type(4))) float  fv4;

#define T_LEN 1024
#define EMB   1024
#define SPAD  1088   // padded src len (17*64), valid 0..1024
#define LOG2E 1.44269504f

// workspace layout (bytes) — packed with lifetime sharing:
//   [0 .. 8.9M)    qx (bf16 query, dead after qkv)  THEN  vt (V^T [64][64][1088])
//   [8.9 .. 16.9M) wt bf16 [4][1024][1024] (W^T)
//   [16.9 .. 24.9M) qb
//   [24.9 .. 33.8M) kb [64][1088][64]
//   [33.8 .. 42.7M) vb row-major [64][1088][64] (dead after vtrans) THEN at
//   tail: gate, pbt, aux
#define OFF_QX   (0ull)
#define OFF_VT   (0ull)
#define OFF_WT   (8912896ull)
#define OFF_QB   (17301504ull)
#define OFF_KB   (25690112ull)
#define OFF_VB   (34603008ull)
#define OFF_AT   (34603008ull)
#define OFF_GATE (43515904ull)
#define OFF_PB   (43778048ull)
#define OFF_AUX  (43909120ull)

__device__ __forceinline__ u16 f2bf(float f) {
  uint32_t u = __builtin_bit_cast(uint32_t, f);
  u += 0x7FFFu + ((u >> 16) & 1u);
  return (u16)(u >> 16);
}
__device__ __forceinline__ float bf2f(u16 s) {
  uint32_t u = ((uint32_t)s) << 16;
  return __builtin_bit_cast(float, u);
}
__device__ __forceinline__ void gld_lds16(const void* gp, void* lp) {
  __builtin_amdgcn_global_load_lds(
      (const __attribute__((address_space(1))) uint32_t*)(uintptr_t)(gp),
      (__attribute__((address_space(3))) uint32_t*)(uintptr_t)(lp),
      16, 0, 0);
}

// ---------------- query f32 -> bf16 ----------------
__global__ void k_convert_q(const float* __restrict__ q, u16* __restrict__ qx) {
  int i = blockIdx.x * 256 + threadIdx.x;
  fv4 v = *((const fv4*)q + i);
  u16x4 o = { f2bf(v[0]), f2bf(v[1]), f2bf(v[2]), f2bf(v[3]) };
  *((u16x4*)qx + i) = o;
}

// ---------------- weight transpose + convert: wt[z][n][k] = w_z[k][n] -------
__global__ void k_transw(const float* __restrict__ w0, const float* __restrict__ w1,
                         const float* __restrict__ w2, const float* __restrict__ w3,
                         u16* __restrict__ wt) {
  __shared__ float tile[32][33];
  const int z = blockIdx.z;
  const float* w = (z == 0) ? w0 : (z == 1) ? w1 : (z == 2) ? w2 : w3;
  const int r0 = blockIdx.y * 32, c0 = blockIdx.x * 32;
  const int tx = threadIdx.x, ty = threadIdx.y;
  #pragma unroll
  for (int j = 0; j < 32; j += 8)
    tile[ty + j][tx] = w[(size_t)(r0 + ty + j) * EMB + c0 + tx];
  __syncthreads();
  u16* o = wt + (size_t)z * EMB * EMB;
  #pragma unroll
  for (int j = 0; j < 32; j += 8)
    o[(size_t)(c0 + ty + j) * EMB + r0 + tx] = f2bf(tile[tx][ty + j]);
}

// ---------------- T5 bucket -> REVERSED bias table + gate aux ---------------
// pbtab[h][i] = pb(rel = 1024 - i) * log2e   (i = 1024 + t - s)
__global__ void k_pb(const float* __restrict__ rel_emb, float* __restrict__ pbtab,
                     const float* __restrict__ grep_w, const float* __restrict__ grep_b,
                     float* __restrict__ aux) {
  int i = blockIdx.x * 256 + threadIdx.x;   // 0..2047
  int rel = 1024 - i;                       // s - t
  int bucket = (rel > 0) ? 16 : 0;
  int r = rel < 0 ? -rel : rel;
  int bidx;
  if (r < 8) bidx = r;
  else {
    float lf = __logf((float)r / 8.0f + 1e-6f) * (1.0f / logf(16.0f)) * 8.0f;
    int large = 8 + (int)lf;
    bidx = large < 15 ? large : 15;
  }
  bucket += bidx;
  #pragma unroll
  for (int h = 0; h < 16; ++h) pbtab[h * 2048 + i] = rel_emb[bucket * 16 + h] * LOG2E;
  if (blockIdx.x == 0) {
    if (threadIdx.x < 64) {
      float s = 0.f;
      #pragma unroll
      for (int j = 0; j < 8; ++j) s += grep_w[threadIdx.x * 8 + j];
      aux[threadIdx.x] = s;
    } else if (threadIdx.x == 64) {
      float s = 0.f;
      #pragma unroll
      for (int j = 0; j < 8; ++j) s += grep_b[j];
      aux[64] = s;
    }
  }
}

// ---------------- m97-style 128x128 bf16 GEMM core (B^T input) --------------
__device__ __forceinline__ void gemm_tile(const u16* __restrict__ A, const u16* __restrict__ Bt,
                                          int m0, int n0, u16* As, u16* Bs, f32x4 acc[4][4]) {
  const int tid = threadIdx.x;
  const int lane = tid & 63, wid = tid >> 6;
  const int wm = wid >> 1, wn = wid & 1;
  const int l15 = lane & 15, l4 = lane >> 4;
  for (int kt = 0; kt < EMB; kt += 32) {
    #pragma unroll
    for (int i = 0; i < 2; ++i) {
      int cw = wid * 64 + i * 256;   // wave-uniform chunk base
      int c = cw + lane;
      int row = c >> 2, cb = c & 3;
      gld_lds16(A  + (size_t)(m0 + row) * EMB + kt + cb * 8, (char*)As + (size_t)cw * 16);
      gld_lds16(Bt + (size_t)(n0 + row) * EMB + kt + cb * 8, (char*)Bs + (size_t)cw * 16);
    }
    __syncthreads();
    short8 a[4], b[4];
    #pragma unroll
    for (int f = 0; f < 4; ++f) {
      a[f] = *(const short8*)(As + (wm * 64 + f * 16 + l15) * 32 + l4 * 8);
      b[f] = *(const short8*)(Bs + (wn * 64 + f * 16 + l15) * 32 + l4 * 8);
    }
    #pragma unroll
    for (int mi = 0; mi < 4; ++mi)
      #pragma unroll
      for (int ni = 0; ni < 4; ++ni)
        acc[mi][ni] = __builtin_amdgcn_mfma_f32_16x16x32_bf16(a[mi], b[ni], acc[mi][ni], 0, 0, 0);
    __syncthreads();
  }
}

// ---------------- fused QKV projection GEMM (N = 3072), scrambled scatter ---
// All three outputs now write d-contiguous 32B chunks (V row-major into vb).
__global__ __launch_bounds__(256, 2) void k_qkv_gemm(const u16* __restrict__ qx, const u16* __restrict__ wt,
    const float* __restrict__ qbias, const float* __restrict__ kbias, const float* __restrict__ vbias,
    u16* __restrict__ qb, u16* __restrict__ kb, u16* __restrict__ vb) {
  __shared__ u16 lds[8192];
  f32x4 acc[4][4];
  #pragma unroll
  for (int i = 0; i < 4; ++i)
    #pragma unroll
    for (int j = 0; j < 4; ++j) acc[i][j] = (f32x4){0.f, 0.f, 0.f, 0.f};
  const int m0 = blockIdx.y * 128, n0g = blockIdx.x * 128;   // n0g in [0,3072)
  gemm_tile(qx, wt, m0, n0g, lds, lds + 4096, acc);          // wt is [3072][1024]
  const int z = n0g >> 10;
  const float* bias = (z == 0) ? qbias : (z == 1) ? kbias : vbias;
  const int lane = threadIdx.x & 63, wid = threadIdx.x >> 6;
  const int wm = wid >> 1, wn = wid & 1, l15 = lane & 15, l4 = lane >> 4;
  #pragma unroll
  for (int ni = 0; ni < 4; ++ni) {
    int colg = n0g + wn * 64 + ni * 16 + l15;
    int col = colg & 1023;
    float bv = bias[col];
    int h = col >> 6, d = col & 63;
    #pragma unroll
    for (int mi = 0; mi < 4; ++mi) {
      #pragma unroll
      for (int r = 0; r < 4; ++r) {
        int row = m0 + wm * 64 + mi * 16 + l4 * 4 + r;
        int t = row >> 2, b = row & 3;     // input rows are (t,b) interleaved
        float v = acc[mi][ni][r] + bv;
        if (z == 0) {
          int x = b * 16 + (t >> 6), u = ((t & 63) << 4) + h;
          qb[((size_t)x * 1024 + u) * 64 + d] = f2bf(v * (LOG2E / 256.0f));
        } else {
          int w = t * 16 + h;
          int j = w / 1025;
          int u = w - j * 1025;
          int x = b * 16 + j;
          if (z == 1) kb[((size_t)x * SPAD + u) * 64 + d] = f2bf(v);
          else        vb[((size_t)x * SPAD + u) * 64 + d] = f2bf(v);
        }
      }
    }
  }
}

// ---------------- bias_k / bias_v rows (row-major, j=15 slots) --------------
__global__ void k_biaskv(const float* __restrict__ bias_k, const float* __restrict__ bias_v,
                         u16* __restrict__ kb, u16* __restrict__ vb) {
  int i = blockIdx.x * 256 + threadIdx.x;  // 0..4095
  int b = i >> 10, h = (i >> 6) & 15, d = i & 63;
  int x = b * 16 + 15, u = 1009 + h;
  kb[((size_t)x * SPAD + u) * 64 + d] = f2bf(bias_k[h * 64 + d]);
  vb[((size_t)x * SPAD + u) * 64 + d] = f2bf(bias_v[h * 64 + d]);
}

// ---------------- V transpose: vb[x][u][d] -> vt[x][d][u] -------------------
// one block per (x, 64-u chunk); coalesced global reads AND writes
__global__ void k_vtrans(const u16* __restrict__ vb, u16* __restrict__ vt) {
  __shared__ u16 t[64][72];
  const int x = blockIdx.y;
  const int u0 = blockIdx.x * 64;
  const int tid = threadIdx.x;
  const int ur = tid >> 2, c0 = (tid & 3) * 16;
  const u16* src = vb + ((size_t)x * SPAD + u0 + ur) * 64 + c0;
  u16x8 a0 = *(const u16x8*)(src);
  u16x8 a1 = *(const u16x8*)(src + 8);
  *(u16x8*)(&t[ur][c0]) = a0;
  *(u16x8*)(&t[ur][c0 + 8]) = a1;
  __syncthreads();
  const int d = tid >> 2, j = tid & 3;    // d row, 16-u chunk j
  u16x8 o0, o1;
  #pragma unroll
  for (int i = 0; i < 8; ++i) o0[i] = t[j * 16 + i][d];
  #pragma unroll
  for (int i = 0; i < 8; ++i) o1[i] = t[j * 16 + 8 + i][d];
  u16* dst = vt + ((size_t)x * 64 + d) * SPAD + u0 + j * 16;
  *(u16x8*)(dst) = o0;
  *(u16x8*)(dst + 8) = o1;
}

// ---------------- gate --------------------------------------------------
__global__ void k_gate(const u16* __restrict__ qb, const float* __restrict__ aux,
                       const float* __restrict__ grep_a, float* __restrict__ gate) {
  int tid = threadIdx.x, lane = tid & 63, wid = tid >> 6;
  int row0 = (blockIdx.x * 4 + wid) * 8;
  int sub = lane >> 3, d0 = (lane & 7) * 8;
  int item = row0 + sub;
  u16x8 q8 = *(const u16x8*)(qb + (size_t)item * 64 + d0);
  float acc = 0.f;
  #pragma unroll
  for (int j = 0; j < 8; ++j) acc += bf2f(q8[j]) * aux[d0 + j];
  acc += __shfl_xor(acc, 1);
  acc += __shfl_xor(acc, 2);
  acc += __shfl_xor(acc, 4);
  if ((lane & 7) == 0) {
    float v = acc * (256.0f / LOG2E) + aux[64];
    float s = 1.0f / (1.0f + __expf(-v));
    gate[item] = s * grep_a[(item >> 10) & 15];
  }
}

// ---------------- fused flash attention v3 ----------------------------------
__global__ __launch_bounds__(256, 2) void k_attn(const u16* __restrict__ qb, const u16* __restrict__ kb,
    const u16* __restrict__ vt, const float* __restrict__ gate, const float* __restrict__ pbt,
    u16* __restrict__ at) {
  __shared__ float pb_s[2048];
  __shared__ u16 Ksh[2 * 4096];   // [buf][64 k][64 d] swizzled
  __shared__ u16 Vsh[2 * 4096];   // [buf][64 d][64 k] swizzled (V^T)
  __shared__ u16 Psh[4 * 2048];   // per-wave [32 q][64 k] swizzled
  const int tid = threadIdx.x, lane = tid & 63, wid = tid >> 6;
  const int l15 = lane & 15, l4 = lane >> 4;
  const int bid = blockIdx.x;
  const int x = (bid & 7) + ((bid >> 6) << 3);   // XCD swizzle
  const int tblk = (bid >> 3) & 7;
  const int h = x & 15, b = x >> 4;
  const int qrow0 = tblk * 128 + wid * 32;

  #pragma unroll
  for (int i = 0; i < 2; ++i) {
    int idx = (tid + i * 256) * 4;
    *(fv4*)(pb_s + idx) = *(const fv4*)(pbt + (size_t)h * 2048 + idx);
  }

  // Q fragments + gate in registers
  short8 qa[2][2];
  #pragma unroll
  for (int pf = 0; pf < 2; ++pf)
    #pragma unroll
    for (int ks = 0; ks < 2; ++ks)
      qa[pf][ks] = *(const short8*)(qb + ((size_t)x * 1024 + qrow0 + pf * 16 + l15) * 64 + ks * 32 + l4 * 8);
  float g[2][4];
  #pragma unroll
  for (int pf = 0; pf < 2; ++pf)
    #pragma unroll
    for (int r = 0; r < 4; ++r)
      g[pf][r] = gate[(size_t)x * 1024 + qrow0 + pf * 16 + l4 * 4 + r];

  // staging source pointers (pre-swizzled global addresses, linear LDS dest)
  const u16* kbx = kb + (size_t)x * SPAD * 64;
  const u16* vtx = vt + (size_t)x * 64 * SPAD;
  const int ra = tid >> 3, sa = tid & 7;          // rows 0..31
  const int rb = ra + 32;                          // rows 32..63
  const u16* sK0 = kbx + ra * 64 + ((sa * 8) ^ ((ra & 7) << 3));
  const u16* sK1 = kbx + rb * 64 + ((sa * 8) ^ ((rb & 7) << 3));
  const u16* sV0 = vtx + (size_t)ra * SPAD + ((sa * 8) ^ ((ra & 7) << 3));
  const u16* sV1 = vtx + (size_t)rb * SPAD + ((sa * 8) ^ ((rb & 7) << 3));

  // fragment read offsets (swizzled)
  const int swz = (l15 & 7) << 3;
  int kfO[4][2];
  #pragma unroll
  for (int f = 0; f < 4; ++f)
    #pragma unroll
    for (int ks = 0; ks < 2; ++ks)
      kfO[f][ks] = (f * 16 + l15) * 64 + ((ks * 32 + l4 * 8) ^ swz);
  int paO[2][2];
  #pragma unroll
  for (int pf = 0; pf < 2; ++pf)
    #pragma unroll
    for (int ks = 0; ks < 2; ++ks)
      paO[pf][ks] = (pf * 16 + l15) * 64 + ((ks * 32 + l4 * 8) ^ swz);
  u16* Pw = Psh + wid * 2048;

  f32x4 O[2][4];
  float l_[2][4];
  #pragma unroll
  for (int pf = 0; pf < 2; ++pf) {
    #pragma unroll
    for (int df = 0; df < 4; ++df) O[pf][df] = (f32x4){0.f, 0.f, 0.f, 0.f};
    #pragma unroll
    for (int r = 0; r < 4; ++r) l_[pf][r] = 0.f;
  }

  // prologue: stage chunk 0 into buf 0
  gld_lds16(sK0, (char*)Ksh + wid * 1024);
  gld_lds16(sK1, (char*)Ksh + 4096 + wid * 1024);
  gld_lds16(sV0, (char*)Vsh + wid * 1024);
  gld_lds16(sV1, (char*)Vsh + 4096 + wid * 1024);
  sK0 += 4096; sK1 += 4096; sV0 += 64; sV1 += 64;
  __asm__ volatile("s_waitcnt vmcnt(0)" ::: "memory");
  __syncthreads();

  int cur = 0;
  for (int ic = 0; ic < 16; ++ic) {
    const int nxt = cur ^ 1;
    char* Kn = (char*)(Ksh + nxt * 4096);
    char* Vn = (char*)(Vsh + nxt * 4096);
    if (ic < 15) {
      gld_lds16(sK0, Kn + wid * 1024);
      gld_lds16(sK1, Kn + 4096 + wid * 1024);
      gld_lds16(sV0, Vn + wid * 1024);
      gld_lds16(sV1, Vn + 4096 + wid * 1024);
      sK0 += 4096; sK1 += 4096; sV0 += 64; sV1 += 64;
    } else if (wid < 2) {
      // stage K tail rows 1024..1039 linearly (only row 0 is real; rest garbage-safe)
      int ro = (wid * 64 + lane) >> 3, so = lane & 7;
      gld_lds16(kbx + (size_t)(1024 + ro) * 64 + so * 8, Kn + wid * 1024);
    }
    const u16* Kc = Ksh + cur * 4096;
    const u16* Vc = Vsh + cur * 4096;

    // QK^T
    f32x4 sc[2][4];
    #pragma unroll
    for (int pf = 0; pf < 2; ++pf)
      #pragma unroll
      for (int nf = 0; nf < 4; ++nf) sc[pf][nf] = (f32x4){0.f, 0.f, 0.f, 0.f};
    #pragma unroll
    for (int nf = 0; nf < 4; ++nf)
      #pragma unroll
      for (int ks = 0; ks < 2; ++ks) {
        short8 kf = *(const short8*)(Kc + kfO[nf][ks]);
        sc[0][nf] = __builtin_amdgcn_mfma_f32_16x16x32_bf16(qa[0][ks], kf, sc[0][nf], 0, 0, 0);
        sc[1][nf] = __builtin_amdgcn_mfma_f32_16x16x32_bf16(qa[1][ks], kf, sc[1][nf], 0, 0, 0);
      }

    // bias + exp2 (fixed max) + partial-l + P store (truncated bf16)
    #pragma unroll
    for (int pf = 0; pf < 2; ++pf)
      #pragma unroll
      for (int nf = 0; nf < 4; ++nf) {
        const int base = 1024 + qrow0 + pf * 16 + l4 * 4 - (ic * 64 + nf * 16 + l15);
        #pragma unroll
        for (int r = 0; r < 4; ++r) {
          float sv = sc[pf][nf][r] + g[pf][r] * pb_s[base + r];
          float p = exp2f(sv);
          l_[pf][r] += p;
          const int prow = pf * 16 + l4 * 4 + r;
          Pw[prow * 64 + ((nf * 16 + l15) ^ ((prow & 7) << 3))] =
              (u16)(__builtin_bit_cast(uint32_t, p) >> 16);
        }
      }
    __asm__ volatile("s_waitcnt lgkmcnt(0)" ::: "memory");
    __builtin_amdgcn_sched_barrier(0);

    // PV
    #pragma unroll
    for (int ks = 0; ks < 2; ++ks) {
      short8 pa0 = *(const short8*)(Pw + paO[0][ks]);
      short8 pa1 = *(const short8*)(Pw + paO[1][ks]);
      #pragma unroll
      for (int df = 0; df < 4; ++df) {
        short8 vbf = *(const short8*)(Vc + kfO[df][ks]);
        O[0][df] = __builtin_amdgcn_mfma_f32_16x16x32_bf16(pa0, vbf, O[0][df], 0, 0, 0);
        O[1][df] = __builtin_amdgcn_mfma_f32_16x16x32_bf16(pa1, vbf, O[1][df], 0, 0, 0);
      }
    }
    __asm__ volatile("s_waitcnt vmcnt(0)" ::: "memory");
    __syncthreads();
    cur = nxt;
  }

  // ---- tail: s = 1024 ----
  const u16* Kt = Ksh + cur * 4096;
  short8 kt0 = *(const short8*)(Kt + l15 * 64 + l4 * 8);
  short8 kt1 = *(const short8*)(Kt + l15 * 64 + 32 + l4 * 8);
  f32x4 sc0[2];
  #pragma unroll
  for (int pf = 0; pf < 2; ++pf) {
    sc0[pf] = (f32x4){0.f, 0.f, 0.f, 0.f};
    sc0[pf] = __builtin_amdgcn_mfma_f32_16x16x32_bf16(qa[pf][0], kt0, sc0[pf], 0, 0, 0);
    sc0[pf] = __builtin_amdgcn_mfma_f32_16x16x32_bf16(qa[pf][1], kt1, sc0[pf], 0, 0, 0);
  }
  float vtail[4];
  #pragma unroll
  for (int df = 0; df < 4; ++df)
    vtail[df] = bf2f(vt[((size_t)x * 64 + df * 16 + l15) * SPAD + 1024]);

  float pt[2][4], linv[2][4];
  #pragma unroll
  for (int pf = 0; pf < 2; ++pf)
    #pragma unroll
    for (int r = 0; r < 4; ++r) {
      float dotv = __shfl(sc0[pf][r], lane & 48);      // col 0 (s=1024)
      int t = qrow0 + pf * 16 + l4 * 4 + r;
      float se = dotv + g[pf][r] * pb_s[t];            // idx = 1024 + t - 1024
      float p = exp2f(se);
      float ls = l_[pf][r];
      ls += __shfl_xor(ls, 1);
      ls += __shfl_xor(ls, 2);
      ls += __shfl_xor(ls, 4);
      ls += __shfl_xor(ls, 8);
      pt[pf][r] = p;
      linv[pf][r] = 1.0f / (ls + p);
    }

  #pragma unroll
  for (int pf = 0; pf < 2; ++pf)
    #pragma unroll
    for (int df = 0; df < 4; ++df)
      #pragma unroll
      for (int r = 0; r < 4; ++r) {
        int t = qrow0 + pf * 16 + l4 * 4 + r;
        float o = (O[pf][df][r] + pt[pf][r] * vtail[df]) * linv[pf][r];
        at[((size_t)(t * 4 + b)) * 1024 + h * 64 + df * 16 + l15] = f2bf(o);
      }
}

// ---------------- output projection GEMM ------------------------------------
__global__ __launch_bounds__(256, 2) void k_out_gemm(const u16* __restrict__ at, const u16* __restrict__ wt3,
                                                     const float* __restrict__ obias, float* __restrict__ out) {
  __shared__ u16 lds[8192];
  f32x4 acc[4][4];
  #pragma unroll
  for (int i = 0; i < 4; ++i)
    #pragma unroll
    for (int j = 0; j < 4; ++j) acc[i][j] = (f32x4){0.f, 0.f, 0.f, 0.f};
  const int m0 = blockIdx.y * 128, n0 = blockIdx.x * 128;
  gemm_tile(at, wt3, m0, n0, lds, lds + 4096, acc);
  const int lane = threadIdx.x & 63, wid = threadIdx.x >> 6;
  const int wm = wid >> 1, wn = wid & 1, l15 = lane & 15, l4 = lane >> 4;
  #pragma unroll
  for (int ni = 0; ni < 4; ++ni) {
    int col = n0 + wn * 64 + ni * 16 + l15;
    float bv = obias[col];
    #pragma unroll
    for (int mi = 0; mi < 4; ++mi) {
      #pragma unroll
      for (int r = 0; r < 4; ++r) {
        int row = m0 + wm * 64 + mi * 16 + l4 * 4 + r;
        out[(size_t)row * 1024 + col] = acc[mi][ni][r] + bv;
      }
    }
  }
}

extern "C" void kernel_launch(void* const* d_in, const int* in_sizes, int n_in,
                              void* d_out, int out_size, void* d_ws, size_t ws_size,
                              hipStream_t stream) {
  const float* query   = (const float*)d_in[0];
  const float* q_w     = (const float*)d_in[1];
  const float* q_b     = (const float*)d_in[2];
  const float* k_w     = (const float*)d_in[3];
  const float* k_b     = (const float*)d_in[4];
  const float* v_w     = (const float*)d_in[5];
  const float* v_b     = (const float*)d_in[6];
  const float* out_w   = (const float*)d_in[7];
  const float* out_b   = (const float*)d_in[8];
  const float* rel_emb = (const float*)d_in[9];
  const float* grep_w  = (const float*)d_in[10];
  const float* grep_b  = (const float*)d_in[11];
  const float* grep_a  = (const float*)d_in[12];
  const float* bias_k  = (const float*)d_in[13];
  const float* bias_v  = (const float*)d_in[14];
  char* ws = (char*)d_ws;
  u16*   qx  = (u16*)(ws + OFF_QX);
  u16*   vt  = (u16*)(ws + OFF_VT);   // shares qx region (qx dead after qkv)
  u16*   wt  = (u16*)(ws + OFF_WT);
  u16*   qb  = (u16*)(ws + OFF_QB);
  u16*   kb  = (u16*)(ws + OFF_KB);
  u16*   vb  = (u16*)(ws + OFF_VB);
  u16*   at  = (u16*)(ws + OFF_AT);   // shares vb region (vb dead after vtrans)
  float* gate = (float*)(ws + OFF_GATE);
  float* pbt  = (float*)(ws + OFF_PB);
  float* aux  = (float*)(ws + OFF_AUX);
  float* out  = (float*)d_out;

  k_convert_q<<<dim3(4096), dim3(256), 0, stream>>>(query, qx);
  k_transw<<<dim3(32, 32, 4), dim3(32, 8), 0, stream>>>(q_w, k_w, v_w, out_w, wt);
  k_pb<<<dim3(8), dim3(256), 0, stream>>>(rel_emb, pbt, grep_w, grep_b, aux);
  k_qkv_gemm<<<dim3(24, 32), dim3(256), 0, stream>>>(qx, wt, q_b, k_b, v_b, qb, kb, vb);
  k_biaskv<<<dim3(16), dim3(256), 0, stream>>>(bias_k, bias_v, kb, vb);
  k_vtrans<<<dim3(17, 64), dim3(256), 0, stream>>>(vb, vt);
  k_gate<<<dim3(2048), dim3(256), 0, stream>>>(qb, aux, grep_a, gate);
  k_attn<<<dim3(512), dim3(256), 0, stream>>>(qb, kb, vt, gate, pbt, at);
  k_out_gemm<<<dim3(8, 32), dim3(256), 0, stream>>>(at, wt + (size_t)3 * EMB * EMB, out_b, out);
}